// Round 14
// baseline (266.044 us; speedup 1.0000x reference)
//
#include <hip/hip_runtime.h>
#include <cstdint>

// ---------------------------------------------------------------------------
// AnaphoricityScorer: scores = rough + FFNN([a, b, a*b, pw] @ W1 -> leaky -> W_out)
// Factorized: h = Ha[batch] + Hb[idx] + (a*b|pw)@W1cd + b1
// R14: R12 + LDS-deepened A prefetch (wave-private, ZERO barriers).
//   R13 analysis: R12 is latency-bound (L2 at 25% util, MFMA 32%, round
//   3500cyc vs 900 floor); VGPR boundary (acc 128 AGPR + 96 operand) blocks
//   deeper reg prefetch AND more waves. Fix: A frags via global_load_lds
//   4-DEEP into wave-private LDS (4x4KB/wave), ds_read_b128 to consume;
//   B stays 2-deep VGPR ping-pong (L2-resident, short latency).
//   FIFO vmcnt ledger (A(k+4) then B(k+2) per iter, sched_barrier-pinned):
//   steady vmcnt(12), tail 8/8/0 -- no drains in the loop.
//   Also: k_cvt kernels dropped; k_pairs gathers f32 with explicit bf16
//   pre-rounding (numerics identical to R12).
// ---------------------------------------------------------------------------

typedef short short8 __attribute__((ext_vector_type(8)));
typedef float f32x4 __attribute__((ext_vector_type(4)));

#define BT_STRIDE 100352  // 98 kc * 1024 B per 16-col W1 tile
#define MT_STRIDE 32768   // 32 kc * 1024 B per 16-row mention tile
#define PT_STRIDE 34816   // 34 kc * 1024 B per 16-row pair tile

static __device__ __forceinline__ unsigned short f2bf(float x) {
  union { float f; unsigned u; } v; v.f = x;
  unsigned r = v.u + 0x7fffu + ((v.u >> 16) & 1u);  // RNE
  return (unsigned short)(r >> 16);
}
static __device__ __forceinline__ float bf2f(unsigned short u) {
  union { unsigned u; float f; } v; v.u = ((unsigned)u) << 16;
  return v.f;
}
static __device__ __forceinline__ float rbf(float x) {  // round f32 -> bf16 value
  return bf2f(f2bf(x));
}

static __device__ __forceinline__ void gload_lds16(const void* g, void* lds) {
  __builtin_amdgcn_global_load_lds(
      (const __attribute__((address_space(1))) void*)(unsigned long long)(uintptr_t)g,
      (__attribute__((address_space(3))) void*)(unsigned)(uintptr_t)lds, 16, 0, 0);
}

// W1 [3136][1024] f32 -> BtAll [64 ct][98 kc][64 lane][8] bf16
__global__ void k_packW(const float* __restrict__ W1, unsigned short* __restrict__ BtAll) {
  __shared__ float t[64][65];
  int k0 = blockIdx.x * 64, n0 = blockIdx.y * 64;
  int c = threadIdx.x & 63, r4 = threadIdx.x >> 6;
#pragma unroll
  for (int rr = 0; rr < 16; ++rr) {
    int r = rr * 4 + r4;
    t[r][c] = W1[(size_t)(k0 + r) * 1024 + n0 + c];
  }
  __syncthreads();
#pragma unroll
  for (int qq = 0; qq < 2; ++qq) {
    int q = threadIdx.x * 2 + qq;
    int cc = q >> 3, rg = q & 7;
    short8 v;
#pragma unroll
    for (int e = 0; e < 8; ++e) v[e] = (short)f2bf(t[rg * 8 + e][cc]);
    int ct = (n0 + cc) >> 4;
    int kc = (k0 >> 5) + (rg >> 2);
    int ln = (cc & 15) + ((rg & 3) << 4);
    *(short8*)((char*)BtAll + (size_t)ct * BT_STRIDE + kc * 1024 + ln * 16) = v;
  }
}

// mentions -> Mt fragment tiles; rt 0..511 = allm rows, rt 512..575 = am rows.
__global__ void k_packM(const float* __restrict__ am, const float* __restrict__ allm,
                        unsigned short* __restrict__ Mt) {
  int rt = blockIdx.x, t = threadIdx.x;
  const float* S = (rt < 512) ? (allm + (size_t)rt * 16 * 1024)
                              : (am + (size_t)(rt - 512) * 16 * 1024);
  int pf = t & 15, oct = (t >> 4) & 3, kcl = t >> 6;
  const float* row = S + (size_t)pf * 1024;
  char* dst = (char*)Mt + (size_t)rt * MT_STRIDE + (t & 63) * 16;
#pragma unroll
  for (int pass = 0; pass < 8; ++pass) {
    int kc = pass * 4 + kcl;
    int k = kc * 32 + oct * 8;
    float4 v0 = *(const float4*)(row + k);
    float4 v1 = *(const float4*)(row + k + 4);
    short8 o;
    o[0] = (short)f2bf(v0.x); o[1] = (short)f2bf(v0.y);
    o[2] = (short)f2bf(v0.z); o[3] = (short)f2bf(v0.w);
    o[4] = (short)f2bf(v1.x); o[5] = (short)f2bf(v1.y);
    o[6] = (short)f2bf(v1.z); o[7] = (short)f2bf(v1.w);
    *(short8*)(dst + kc * 1024) = o;
  }
}

// Pair tiles from f32 sources (values pre-rounded to bf16 => numerics
// identical to the bf16-source version). Block = one rt (16 pairs).
__global__ void k_pairs(const float* __restrict__ am, const float* __restrict__ allm,
                        const float* __restrict__ pw, const int* __restrict__ idx,
                        unsigned short* __restrict__ Pt) {
  __shared__ int g16[16];
  int rt = blockIdx.x, t = threadIdx.x;
  if (t < 16) g16[t] = idx[rt * 16 + t];
  __syncthreads();
  int pf = t & 15, oct = (t >> 4) & 3, kcl = t >> 6;
  int p = rt * 16 + pf;
  const float* arow = am + (size_t)(p / 50) * 1024;
  const float* brow = allm + (size_t)g16[pf] * 1024;
  char* dst = (char*)Pt + (size_t)rt * PT_STRIDE + (t & 63) * 16;
#pragma unroll
  for (int pass = 0; pass < 8; ++pass) {
    int kc = pass * 4 + kcl;
    int k = kc * 32 + oct * 8;
    float4 a0 = *(const float4*)(arow + k);
    float4 a1 = *(const float4*)(arow + k + 4);
    float4 b0 = *(const float4*)(brow + k);
    float4 b1 = *(const float4*)(brow + k + 4);
    short8 o;
    o[0] = (short)f2bf(rbf(a0.x) * rbf(b0.x));
    o[1] = (short)f2bf(rbf(a0.y) * rbf(b0.y));
    o[2] = (short)f2bf(rbf(a0.z) * rbf(b0.z));
    o[3] = (short)f2bf(rbf(a0.w) * rbf(b0.w));
    o[4] = (short)f2bf(rbf(a1.x) * rbf(b1.x));
    o[5] = (short)f2bf(rbf(a1.y) * rbf(b1.y));
    o[6] = (short)f2bf(rbf(a1.z) * rbf(b1.z));
    o[7] = (short)f2bf(rbf(a1.w) * rbf(b1.w));
    *(short8*)(dst + kc * 1024) = o;
  }
  if (t < 128) {
    int kc = 32 + (t >> 6);
    int kpw = (t >> 6) * 32 + oct * 8;
    const float* prow = pw + (size_t)p * 64;
    float4 v0 = *(const float4*)(prow + kpw);
    float4 v1 = *(const float4*)(prow + kpw + 4);
    short8 o;
    o[0] = (short)f2bf(v0.x); o[1] = (short)f2bf(v0.y);
    o[2] = (short)f2bf(v0.z); o[3] = (short)f2bf(v0.w);
    o[4] = (short)f2bf(v1.x); o[5] = (short)f2bf(v1.y);
    o[6] = (short)f2bf(v1.z); o[7] = (short)f2bf(v1.w);
    *(short8*)(dst + kc * 1024) = o;
  }
}

// Wave-independent pre-packed GEMM; A via 4-deep wave-private LDS pipeline,
// B via 2-deep VGPR ping-pong. 4 waves/block share a 128-col B panel.
// MODE 0: Ha+Hb fused store. MODE 1: main GEMM + fused scorer epilogue.
template <int MODE>
__global__ __launch_bounds__(256, 2) void k_gt(
    const unsigned short* __restrict__ At, const unsigned short* __restrict__ BtAll,
    float* __restrict__ C, float* __restrict__ partial,
    const float* __restrict__ Hab, const float* __restrict__ b1,
    const float* __restrict__ Wout, const int* __restrict__ idx) {
  constexpr int NKC = MODE ? 34 : 32;
  constexpr int A_STRIDE = MODE ? PT_STRIDE : MT_STRIDE;
  __shared__ char AL[4][4][4096];  // [wave][depth-4 bufs][4 x 1KB frag slabs]
  int tid = threadIdx.x, lane = tid & 63, wave = tid >> 6;
  int llo = lane & 15, lhi = lane >> 4;
  int id = blockIdx.x;
  int x, y;
  if (MODE == 1) {
    int r = id >> 3;
    x = (id & 7) * 25 + (r >> 3);
    y = r & 7;
  } else {
    x = id >> 3;
    y = id & 7;
  }
  int kcoff = MODE ? 64 : ((x < 32) ? 32 : 0);
  int row0 = x * 256 + wave * 64;
  int n0 = y * 128;
  const char* pa = (const char*)At + (size_t)(row0 >> 4) * A_STRIDE + lane * 16;
  const char* pb = (const char*)BtAll + (size_t)(n0 >> 4) * BT_STRIDE +
                   (size_t)kcoff * 1024 + lane * 16;
  char* myA = &AL[wave][0][0];

  f32x4 acc[4][8] = {};
  short8 breg0[8], breg1[8];

  // A-stage: 4 gload_lds into buf (kt&3); dest is wave-uniform base (HW adds lane*16)
#define A_STAGE(KT)                                                             \
  {                                                                             \
    char* db = myA + ((KT) & 3) * 4096;                                         \
    _Pragma("unroll")                                                           \
    for (int m = 0; m < 4; ++m)                                                 \
      gload_lds16(pa + (size_t)m * A_STRIDE + (KT) * 1024, db + m * 1024);      \
  }
#define B_LOAD(KT, BREG)                                                        \
  {                                                                             \
    _Pragma("unroll")                                                           \
    for (int n = 0; n < 8; ++n)                                                 \
      BREG[n] = *(const short8*)(pb + (size_t)n * BT_STRIDE + (KT) * 1024);     \
  }

  // prologue, FIFO order: A0 A1 A2 B0 A3 B1  -> steady invariant vmcnt(12)
  A_STAGE(0);
  __builtin_amdgcn_sched_barrier(0);
  A_STAGE(1);
  __builtin_amdgcn_sched_barrier(0);
  A_STAGE(2);
  __builtin_amdgcn_sched_barrier(0);
  B_LOAD(0, breg0);
  __builtin_amdgcn_sched_barrier(0);
  A_STAGE(3);
  __builtin_amdgcn_sched_barrier(0);
  B_LOAD(1, breg1);
  __builtin_amdgcn_sched_barrier(0);

#define GT_ITER(KT, BREG)                                                       \
  {                                                                             \
    if ((KT) < NKC - 3)      asm volatile("s_waitcnt vmcnt(12)" ::: "memory");  \
    else if ((KT) < NKC - 1) asm volatile("s_waitcnt vmcnt(8)" ::: "memory");   \
    else                     asm volatile("s_waitcnt vmcnt(0)" ::: "memory");   \
    __builtin_amdgcn_sched_barrier(0);                                          \
    const char* rb = myA + ((KT) & 3) * 4096;                                   \
    short8 af[4];                                                               \
    _Pragma("unroll")                                                           \
    for (int m = 0; m < 4; ++m)                                                 \
      af[m] = *(const short8*)(rb + m * 1024 + lane * 16);                      \
    _Pragma("unroll")                                                           \
    for (int m = 0; m < 4; ++m)                                                 \
      _Pragma("unroll")                                                         \
      for (int n = 0; n < 8; ++n)                                               \
        acc[m][n] = __builtin_amdgcn_mfma_f32_16x16x32_bf16(af[m], BREG[n],     \
                                                            acc[m][n], 0, 0, 0);\
    __builtin_amdgcn_sched_barrier(0);                                          \
    if ((KT) + 4 < NKC) { A_STAGE((KT) + 4); }                                  \
    __builtin_amdgcn_sched_barrier(0);                                          \
    if ((KT) + 2 < NKC) { B_LOAD((KT) + 2, BREG); }                             \
    __builtin_amdgcn_sched_barrier(0);                                          \
  }

#pragma unroll
  for (int kt2 = 0; kt2 < NKC; kt2 += 2) {
    GT_ITER(kt2, breg0);
    GT_ITER(kt2 + 1, breg1);
  }
#undef GT_ITER
#undef A_STAGE
#undef B_LOAD

  if (MODE == 0) {
#pragma unroll
    for (int m = 0; m < 4; ++m)
#pragma unroll
      for (int i = 0; i < 4; ++i) {
        int row = row0 + m * 16 + lhi * 4 + i;
#pragma unroll
        for (int n = 0; n < 8; ++n)
          C[(size_t)row * 1024 + n0 + n * 16 + llo] = acc[m][n][i];
      }
  } else {
    float b1v[8], wov[8];
    int coln[8];
#pragma unroll
    for (int n = 0; n < 8; ++n) {
      coln[n] = n0 + n * 16 + llo;
      b1v[n] = b1[coln[n]];
      wov[n] = Wout[coln[n]];
    }
#pragma unroll
    for (int m = 0; m < 4; ++m)
#pragma unroll
      for (int i = 0; i < 4; ++i) {
        int p = row0 + m * 16 + lhi * 4 + i;
        int bb = p / 50;
        int gg = idx[p];
        const float* Har = Hab + (size_t)(8192 + bb) * 1024;
        const float* Hbr = Hab + (size_t)gg * 1024;
        float s0 = 0.f, s1 = 0.f;
#pragma unroll
        for (int n = 0; n < 4; ++n) {
          float h = acc[m][n][i] + Har[coln[n]] + Hbr[coln[n]] + b1v[n];
          h = h > 0.f ? h : 0.01f * h;
          s0 += h * wov[n];
        }
#pragma unroll
        for (int n = 4; n < 8; ++n) {
          float h = acc[m][n][i] + Har[coln[n]] + Hbr[coln[n]] + b1v[n];
          h = h > 0.f ? h : 0.01f * h;
          s1 += h * wov[n];
        }
        s0 += __shfl_xor(s0, 1, 64);
        s0 += __shfl_xor(s0, 2, 64);
        s0 += __shfl_xor(s0, 4, 64);
        s0 += __shfl_xor(s0, 8, 64);
        s1 += __shfl_xor(s1, 1, 64);
        s1 += __shfl_xor(s1, 2, 64);
        s1 += __shfl_xor(s1, 4, 64);
        s1 += __shfl_xor(s1, 8, 64);
        if (llo == 0) {
          partial[(size_t)p * 16 + y * 2 + 0] = s0;
          partial[(size_t)p * 16 + y * 2 + 1] = s1;
        }
      }
  }
}

__global__ void k_final(const float* __restrict__ partial, const float* __restrict__ rough,
                        const float* __restrict__ bout, float* __restrict__ out) {
  int t = blockIdx.x * 256 + threadIdx.x;
  if (t < 51200) {
    float s = rough[t] + bout[0];
    const float* pp = partial + (size_t)t * 16;
#pragma unroll
    for (int c = 0; c < 16; ++c) s += pp[c];
    out[(size_t)(t / 50) * 51 + 1 + (t % 50)] = s;
  }
  if (t < 1024) out[(size_t)t * 51] = 1e-7f;
}

extern "C" void kernel_launch(void* const* d_in, const int* in_sizes, int n_in,
                              void* d_out, int out_size, void* d_ws, size_t ws_size,
                              hipStream_t stream) {
  (void)in_sizes; (void)n_in; (void)out_size;
  const float* allm  = (const float*)d_in[0];  // [8192][1024]
  const float* am    = (const float*)d_in[1];  // [1024][1024]
  const float* pw    = (const float*)d_in[2];  // [1024][50][64]
  const float* rough = (const float*)d_in[3];  // [1024][50]
  const float* W1    = (const float*)d_in[4];  // [3136][1024]
  const float* b1    = (const float*)d_in[5];  // [1024]
  const float* Wout  = (const float*)d_in[6];  // [1024]
  const float* bout  = (const float*)d_in[7];  // [1]
  const int*   idx   = (const int*)d_in[8];    // [1024][50]
  float* out = (float*)d_out;                  // [1024][51]

  char* w = (char*)d_ws;
  unsigned short* BtAll = (unsigned short*)w; w += (size_t)64 * BT_STRIDE;
  unsigned short* Mt    = (unsigned short*)w; w += (size_t)576 * MT_STRIDE;
  unsigned short* Pt    = (unsigned short*)w; w += (size_t)3200 * PT_STRIDE;
  float* Hab            = (float*)w;          w += (size_t)9216 * 1024 * 4;
  float* part           = (float*)w;          w += (size_t)51200 * 16 * 4;
  size_t need = (size_t)(w - (char*)d_ws);
  if (ws_size < need) return;

  k_packW<<<dim3(49, 16), 256, 0, stream>>>(W1, BtAll);
  k_packM<<<dim3(576), 256, 0, stream>>>(am, allm, Mt);
  k_pairs<<<dim3(3200), 256, 0, stream>>>(am, allm, pw, idx, Pt);
  // Ha+Hb fused: 9216 rows -> 36 x-blocks * 8 y = 288 blocks
  k_gt<0><<<dim3(288), 256, 0, stream>>>(Mt, BtAll, Hab, nullptr,
                                         nullptr, nullptr, nullptr, nullptr);
  // main: 51200 rows -> 200 x * 8 y = 1600 blocks, XCD swizzle
  k_gt<1><<<dim3(1600), 256, 0, stream>>>(Pt, BtAll, nullptr, part,
                                          Hab, b1, Wout, idx);
  k_final<<<dim3(200), 256, 0, stream>>>(part, rough, bout, out);
}

// Round 15
// 254.072 us; speedup vs baseline: 1.0471x; 1.0471x over previous
//
#include <hip/hip_runtime.h>
#include <cstdint>

// ---------------------------------------------------------------------------
// AnaphoricityScorer: scores = rough + FFNN([a, b, a*b, pw] @ W1 -> leaky -> W_out)
// Factorized: h = Ha[batch] + Hb[idx] + (a*b|pw)@W1cd + b1
// R15: R12 baseline + A-SHARED wave layout in k_gt.
//   4 waves/block now cover the SAME 64 A-rows and each owns a distinct
//   128-col B panel (block = 64 rows x 512 cols). A frags (the HBM/L3
//   stream) become the shared operand: 4KB/kc/block via L1 instead of
//   16KB distinct; block traffic 48->36 KB/kc; A re-read factor 8->2.
//   Everything else byte-identical to R12's proven 155us kernel: 2-deep
//   register ping-pong, no LDS, no barriers, compiler scheduling.
//   (R13 dual-path and R14 4-deep LDS were null: occupancy is reg-capped
//   at 2 waves/SIMD; traffic mix is the remaining in-structure lever.)
//   k_cvt + bf16-source k_pairs restored (R14's f32 gathers cost ~10us).
// ---------------------------------------------------------------------------

typedef short short8 __attribute__((ext_vector_type(8)));
typedef float f32x4 __attribute__((ext_vector_type(4)));

#define BT_STRIDE 100352  // 98 kc * 1024 B per 16-col W1 tile
#define MT_STRIDE 32768   // 32 kc * 1024 B per 16-row mention tile
#define PT_STRIDE 34816   // 34 kc * 1024 B per 16-row pair tile

static __device__ __forceinline__ unsigned short f2bf(float x) {
  union { float f; unsigned u; } v; v.f = x;
  unsigned r = v.u + 0x7fffu + ((v.u >> 16) & 1u);  // RNE
  return (unsigned short)(r >> 16);
}
static __device__ __forceinline__ float bf2f(unsigned short u) {
  union { unsigned u; float f; } v; v.u = ((unsigned)u) << 16;
  return v.f;
}

// W1 [3136][1024] f32 -> BtAll [64 ct][98 kc][64 lane][8] bf16
__global__ void k_packW(const float* __restrict__ W1, unsigned short* __restrict__ BtAll) {
  __shared__ float t[64][65];
  int k0 = blockIdx.x * 64, n0 = blockIdx.y * 64;
  int c = threadIdx.x & 63, r4 = threadIdx.x >> 6;
#pragma unroll
  for (int rr = 0; rr < 16; ++rr) {
    int r = rr * 4 + r4;
    t[r][c] = W1[(size_t)(k0 + r) * 1024 + n0 + c];
  }
  __syncthreads();
#pragma unroll
  for (int qq = 0; qq < 2; ++qq) {
    int q = threadIdx.x * 2 + qq;
    int cc = q >> 3, rg = q & 7;
    short8 v;
#pragma unroll
    for (int e = 0; e < 8; ++e) v[e] = (short)f2bf(t[rg * 8 + e][cc]);
    int ct = (n0 + cc) >> 4;
    int kc = (k0 >> 5) + (rg >> 2);
    int ln = (cc & 15) + ((rg & 3) << 4);
    *(short8*)((char*)BtAll + (size_t)ct * BT_STRIDE + kc * 1024 + ln * 16) = v;
  }
}

__global__ void k_cvt(const float* __restrict__ s, unsigned short* __restrict__ d, int n4) {
  int i = blockIdx.x * 256 + threadIdx.x;
  if (i < n4) {
    float4 v = ((const float4*)s)[i];
    ushort4 o; o.x = f2bf(v.x); o.y = f2bf(v.y); o.z = f2bf(v.z); o.w = f2bf(v.w);
    ((ushort4*)d)[i] = o;
  }
}

// mentions -> Mt fragment tiles; rt 0..511 = allm rows, rt 512..575 = am rows.
__global__ void k_packM(const float* __restrict__ am, const float* __restrict__ allm,
                        unsigned short* __restrict__ Mt) {
  int rt = blockIdx.x, t = threadIdx.x;
  const float* S = (rt < 512) ? (allm + (size_t)rt * 16 * 1024)
                              : (am + (size_t)(rt - 512) * 16 * 1024);
  int pf = t & 15, oct = (t >> 4) & 3, kcl = t >> 6;
  const float* row = S + (size_t)pf * 1024;
  char* dst = (char*)Mt + (size_t)rt * MT_STRIDE + (t & 63) * 16;
#pragma unroll
  for (int pass = 0; pass < 8; ++pass) {
    int kc = pass * 4 + kcl;
    int k = kc * 32 + oct * 8;
    float4 v0 = *(const float4*)(row + k);
    float4 v1 = *(const float4*)(row + k + 4);
    short8 o;
    o[0] = (short)f2bf(v0.x); o[1] = (short)f2bf(v0.y);
    o[2] = (short)f2bf(v0.z); o[3] = (short)f2bf(v0.w);
    o[4] = (short)f2bf(v1.x); o[5] = (short)f2bf(v1.y);
    o[6] = (short)f2bf(v1.z); o[7] = (short)f2bf(v1.w);
    *(short8*)(dst + kc * 1024) = o;
  }
}

// Pair tiles: block = one rt (16 pairs), coalesced 1KB slab writes, bf16 srcs.
__global__ void k_pairs(const unsigned short* __restrict__ Abm,
                        const unsigned short* __restrict__ Aball,
                        const float* __restrict__ pw, const int* __restrict__ idx,
                        unsigned short* __restrict__ Pt) {
  __shared__ int g16[16];
  int rt = blockIdx.x, t = threadIdx.x;
  if (t < 16) g16[t] = idx[rt * 16 + t];
  __syncthreads();
  int pf = t & 15, oct = (t >> 4) & 3, kcl = t >> 6;
  int p = rt * 16 + pf;
  const unsigned short* arow = Abm + (size_t)(p / 50) * 1024;
  const unsigned short* brow = Aball + (size_t)g16[pf] * 1024;
  char* dst = (char*)Pt + (size_t)rt * PT_STRIDE + (t & 63) * 16;
#pragma unroll
  for (int pass = 0; pass < 8; ++pass) {
    int kc = pass * 4 + kcl;
    int k = kc * 32 + oct * 8;
    short8 a8 = *(const short8*)(arow + k);
    short8 b8 = *(const short8*)(brow + k);
    short8 o;
#pragma unroll
    for (int e = 0; e < 8; ++e)
      o[e] = (short)f2bf(bf2f((unsigned short)a8[e]) * bf2f((unsigned short)b8[e]));
    *(short8*)(dst + kc * 1024) = o;
  }
  if (t < 128) {
    int kc = 32 + (t >> 6);
    int kpw = (t >> 6) * 32 + oct * 8;
    const float* prow = pw + (size_t)p * 64;
    float4 v0 = *(const float4*)(prow + kpw);
    float4 v1 = *(const float4*)(prow + kpw + 4);
    short8 o;
    o[0] = (short)f2bf(v0.x); o[1] = (short)f2bf(v0.y);
    o[2] = (short)f2bf(v0.z); o[3] = (short)f2bf(v0.w);
    o[4] = (short)f2bf(v1.x); o[5] = (short)f2bf(v1.y);
    o[6] = (short)f2bf(v1.z); o[7] = (short)f2bf(v1.w);
    *(short8*)(dst + kc * 1024) = o;
  }
}

// Wave-independent pre-packed GEMM, A-SHARED layout: 4 waves cover the SAME
// 64 rows; wave w owns cols [y*512 + w*128, +128). 2-deep reg ping-pong,
// no LDS, no barriers.
// MODE 0: Ha+Hb fused store (grid 288 = 144 x-tiles * 2 y).
// MODE 1: main GEMM + fused scorer epilogue (grid 1600 = 800 x * 2 y, XCD).
template <int MODE>
__global__ __launch_bounds__(256, 2) void k_gt(
    const unsigned short* __restrict__ At, const unsigned short* __restrict__ BtAll,
    float* __restrict__ C, float* __restrict__ partial,
    const float* __restrict__ Hab, const float* __restrict__ b1,
    const float* __restrict__ Wout, const int* __restrict__ idx) {
  constexpr int NKC = MODE ? 34 : 32;
  constexpr int A_STRIDE = MODE ? PT_STRIDE : MT_STRIDE;
  int tid = threadIdx.x, lane = tid & 63, wave = tid >> 6;
  int llo = lane & 15, lhi = lane >> 4;
  int id = blockIdx.x;
  int x, y;
  if (MODE == 1) {
    int r = id >> 3;                 // 0..199
    x = (id & 7) * 100 + (r >> 1);   // 100 x-tiles per XCD chunk
    y = r & 1;
  } else {
    x = id >> 1;
    y = id & 1;
  }
  int kcoff = MODE ? 64 : ((x < 128) ? 32 : 0);
  int row0 = x * 64;
  int n0w = y * 512 + wave * 128;
  const char* pa = (const char*)At + (size_t)(row0 >> 4) * A_STRIDE + lane * 16;
  const char* pb = (const char*)BtAll + (size_t)(n0w >> 4) * BT_STRIDE +
                   (size_t)kcoff * 1024 + lane * 16;

  f32x4 acc[4][8] = {};
  short8 aA[4], bA[8], aB[4], bB[8];
#pragma unroll
  for (int m = 0; m < 4; ++m) aA[m] = *(const short8*)(pa + (size_t)m * A_STRIDE);
#pragma unroll
  for (int n = 0; n < 8; ++n) bA[n] = *(const short8*)(pb + (size_t)n * BT_STRIDE);
  for (int kt = 0; kt < NKC; kt += 2) {
#pragma unroll
    for (int m = 0; m < 4; ++m)
      aB[m] = *(const short8*)(pa + (size_t)m * A_STRIDE + (kt + 1) * 1024);
#pragma unroll
    for (int n = 0; n < 8; ++n)
      bB[n] = *(const short8*)(pb + (size_t)n * BT_STRIDE + (kt + 1) * 1024);
#pragma unroll
    for (int m = 0; m < 4; ++m)
#pragma unroll
      for (int n = 0; n < 8; ++n)
        acc[m][n] = __builtin_amdgcn_mfma_f32_16x16x32_bf16(aA[m], bA[n], acc[m][n], 0, 0, 0);
    if (kt + 2 < NKC) {
#pragma unroll
      for (int m = 0; m < 4; ++m)
        aA[m] = *(const short8*)(pa + (size_t)m * A_STRIDE + (kt + 2) * 1024);
#pragma unroll
      for (int n = 0; n < 8; ++n)
        bA[n] = *(const short8*)(pb + (size_t)n * BT_STRIDE + (kt + 2) * 1024);
    }
#pragma unroll
    for (int m = 0; m < 4; ++m)
#pragma unroll
      for (int n = 0; n < 8; ++n)
        acc[m][n] = __builtin_amdgcn_mfma_f32_16x16x32_bf16(aB[m], bB[n], acc[m][n], 0, 0, 0);
  }

  if (MODE == 0) {
#pragma unroll
    for (int m = 0; m < 4; ++m)
#pragma unroll
      for (int i = 0; i < 4; ++i) {
        int row = row0 + m * 16 + lhi * 4 + i;
#pragma unroll
        for (int n = 0; n < 8; ++n)
          C[(size_t)row * 1024 + n0w + n * 16 + llo] = acc[m][n][i];
      }
  } else {
    float b1v[8], wov[8];
    int coln[8];
#pragma unroll
    for (int n = 0; n < 8; ++n) {
      coln[n] = n0w + n * 16 + llo;
      b1v[n] = b1[coln[n]];
      wov[n] = Wout[coln[n]];
    }
    int chunk = n0w >> 6;  // y*8 + wave*2
#pragma unroll
    for (int m = 0; m < 4; ++m)
#pragma unroll
      for (int i = 0; i < 4; ++i) {
        int p = row0 + m * 16 + lhi * 4 + i;
        int bb = p / 50;
        int gg = idx[p];
        const float* Har = Hab + (size_t)(8192 + bb) * 1024;
        const float* Hbr = Hab + (size_t)gg * 1024;
        float s0 = 0.f, s1 = 0.f;
#pragma unroll
        for (int n = 0; n < 4; ++n) {
          float h = acc[m][n][i] + Har[coln[n]] + Hbr[coln[n]] + b1v[n];
          h = h > 0.f ? h : 0.01f * h;
          s0 += h * wov[n];
        }
#pragma unroll
        for (int n = 4; n < 8; ++n) {
          float h = acc[m][n][i] + Har[coln[n]] + Hbr[coln[n]] + b1v[n];
          h = h > 0.f ? h : 0.01f * h;
          s1 += h * wov[n];
        }
        s0 += __shfl_xor(s0, 1, 64);
        s0 += __shfl_xor(s0, 2, 64);
        s0 += __shfl_xor(s0, 4, 64);
        s0 += __shfl_xor(s0, 8, 64);
        s1 += __shfl_xor(s1, 1, 64);
        s1 += __shfl_xor(s1, 2, 64);
        s1 += __shfl_xor(s1, 4, 64);
        s1 += __shfl_xor(s1, 8, 64);
        if (llo == 0) {
          partial[(size_t)p * 16 + chunk + 0] = s0;
          partial[(size_t)p * 16 + chunk + 1] = s1;
        }
      }
  }
}

__global__ void k_final(const float* __restrict__ partial, const float* __restrict__ rough,
                        const float* __restrict__ bout, float* __restrict__ out) {
  int t = blockIdx.x * 256 + threadIdx.x;
  if (t < 51200) {
    float s = rough[t] + bout[0];
    const float* pp = partial + (size_t)t * 16;
#pragma unroll
    for (int c = 0; c < 16; ++c) s += pp[c];
    out[(size_t)(t / 50) * 51 + 1 + (t % 50)] = s;
  }
  if (t < 1024) out[(size_t)t * 51] = 1e-7f;
}

extern "C" void kernel_launch(void* const* d_in, const int* in_sizes, int n_in,
                              void* d_out, int out_size, void* d_ws, size_t ws_size,
                              hipStream_t stream) {
  (void)in_sizes; (void)n_in; (void)out_size;
  const float* allm  = (const float*)d_in[0];  // [8192][1024]
  const float* am    = (const float*)d_in[1];  // [1024][1024]
  const float* pw    = (const float*)d_in[2];  // [1024][50][64]
  const float* rough = (const float*)d_in[3];  // [1024][50]
  const float* W1    = (const float*)d_in[4];  // [3136][1024]
  const float* b1    = (const float*)d_in[5];  // [1024]
  const float* Wout  = (const float*)d_in[6];  // [1024]
  const float* bout  = (const float*)d_in[7];  // [1]
  const int*   idx   = (const int*)d_in[8];    // [1024][50]
  float* out = (float*)d_out;                  // [1024][51]

  char* w = (char*)d_ws;
  unsigned short* BtAll = (unsigned short*)w; w += (size_t)64 * BT_STRIDE;
  unsigned short* Mt    = (unsigned short*)w; w += (size_t)576 * MT_STRIDE;
  unsigned short* Abm   = (unsigned short*)w; w += (size_t)1024 * 1024 * 2;
  unsigned short* Aball = (unsigned short*)w; w += (size_t)8192 * 1024 * 2;
  unsigned short* Pt    = (unsigned short*)w; w += (size_t)3200 * PT_STRIDE;
  float* Hab            = (float*)w;          w += (size_t)9216 * 1024 * 4;
  float* part           = (float*)w;          w += (size_t)51200 * 16 * 4;
  size_t need = (size_t)(w - (char*)d_ws);
  if (ws_size < need) return;

  k_packW<<<dim3(49, 16), 256, 0, stream>>>(W1, BtAll);
  k_cvt<<<dim3(1024), 256, 0, stream>>>(am, Abm, 1024 * 1024 / 4);
  k_cvt<<<dim3(8192), 256, 0, stream>>>(allm, Aball, 8192 * 1024 / 4);
  k_packM<<<dim3(576), 256, 0, stream>>>(am, allm, Mt);
  k_pairs<<<dim3(3200), 256, 0, stream>>>(Abm, Aball, pw, idx, Pt);
  // Ha+Hb fused: 9216 rows -> 144 x-tiles * 2 y = 288 blocks
  k_gt<0><<<dim3(288), 256, 0, stream>>>(Mt, BtAll, Hab, nullptr,
                                         nullptr, nullptr, nullptr, nullptr);
  // main: 51200 rows -> 800 x * 2 y = 1600 blocks, XCD swizzle
  k_gt<1><<<dim3(1600), 256, 0, stream>>>(Pt, BtAll, nullptr, part,
                                          Hab, b1, Wout, idx);
  k_final<<<dim3(200), 256, 0, stream>>>(part, rough, bout, out);
}